// Round 7
// baseline (760.253 us; speedup 1.0000x reference)
//
#include <hip/hip_runtime.h>
#include <math.h>

#define BB 2
#define TT 2048
#define DD 2048
#define HH 16
#define KK 128

typedef _Float16 h4 __attribute__((ext_vector_type(4)));
typedef _Float16 v8h __attribute__((ext_vector_type(8)));
typedef float v4f __attribute__((ext_vector_type(4)));
typedef float f2 __attribute__((ext_vector_type(2)));
typedef unsigned int u2v __attribute__((ext_vector_type(2)));

// ---------------------------------------------------------------------------
// FALLBACK fp32 GEMM — used only if ws is too small for the f16 buffers.
// ---------------------------------------------------------------------------
__global__ __launch_bounds__(256) void gemm_nt3(const float* __restrict__ A,
                                                const float* __restrict__ W0,
                                                const float* __restrict__ W1,
                                                const float* __restrict__ W2,
                                                float* __restrict__ Cbase,
                                                int M, int N, int Kd) {
  __shared__ float As[8][128];
  __shared__ float Bs[8][128];
  const int z = blockIdx.z;
  const float* W = (z == 0) ? W0 : (z == 1) ? W1 : W2;
  float* C = Cbase + (size_t)z * M * N;
  const int tid = threadIdx.x;
  const int bm = blockIdx.y * 128;
  const int bn = blockIdx.x * 128;
  const int lrow = tid >> 1;
  const int lcol = (tid & 1) * 4;
  const int rm = (tid >> 4) * 8;
  const int rn = (tid & 15) * 8;
  const float* Ap = A + (size_t)(bm + lrow) * Kd + lcol;
  const float* Wp = W + (size_t)(bn + lrow) * Kd + lcol;
  float acc[8][8];
#pragma unroll
  for (int i = 0; i < 8; i++)
#pragma unroll
    for (int j = 0; j < 8; j++) acc[i][j] = 0.f;
  float4 av = *(const float4*)Ap;
  float4 wv = *(const float4*)Wp;
  for (int d0 = 0; d0 < Kd; d0 += 8) {
    __syncthreads();
    As[lcol + 0][lrow] = av.x; As[lcol + 1][lrow] = av.y;
    As[lcol + 2][lrow] = av.z; As[lcol + 3][lrow] = av.w;
    Bs[lcol + 0][lrow] = wv.x; Bs[lcol + 1][lrow] = wv.y;
    Bs[lcol + 2][lrow] = wv.z; Bs[lcol + 3][lrow] = wv.w;
    __syncthreads();
    if (d0 + 8 < Kd) {
      av = *(const float4*)(Ap + d0 + 8);
      wv = *(const float4*)(Wp + d0 + 8);
    }
#pragma unroll
    for (int kk = 0; kk < 8; kk++) {
      const float4 a0 = *(const float4*)&As[kk][rm];
      const float4 a1 = *(const float4*)&As[kk][rm + 4];
      const float4 b0 = *(const float4*)&Bs[kk][rn];
      const float4 b1 = *(const float4*)&Bs[kk][rn + 4];
      const float ar[8] = {a0.x, a0.y, a0.z, a0.w, a1.x, a1.y, a1.z, a1.w};
      const float br[8] = {b0.x, b0.y, b0.z, b0.w, b1.x, b1.y, b1.z, b1.w};
#pragma unroll
      for (int i = 0; i < 8; i++)
#pragma unroll
        for (int j = 0; j < 8; j++) acc[i][j] = fmaf(ar[i], br[j], acc[i][j]);
    }
  }
#pragma unroll
  for (int i = 0; i < 8; i++) {
    float* cp = C + (size_t)(bm + rm + i) * N + bn + rn;
    float4 c0 = {acc[i][0], acc[i][1], acc[i][2], acc[i][3]};
    float4 c1 = {acc[i][4], acc[i][5], acc[i][6], acc[i][7]};
    *(float4*)cp = c0;
    *(float4*)(cp + 4) = c1;
  }
}

// ---------------------------------------------------------------------------
// Convert: x -> xh (single f16), Wq/Wk/Wv -> Wf (single f16).
// ---------------------------------------------------------------------------
__global__ __launch_bounds__(256) void convert_f16(
    const float* __restrict__ x, const float* __restrict__ Wq,
    const float* __restrict__ Wk, const float* __restrict__ Wv,
    _Float16* __restrict__ xh, _Float16* __restrict__ Wf) {
  const size_t N4X = (size_t)BB * TT * DD / 4;
  const size_t N4W = (size_t)(HH * KK) * DD / 4;
  const size_t i = (size_t)blockIdx.x * 256 + threadIdx.x;
  if (i < N4X) {
    const float4 v = ((const float4*)x)[i];
    h4 hi;
    hi.x = (_Float16)v.x; hi.y = (_Float16)v.y;
    hi.z = (_Float16)v.z; hi.w = (_Float16)v.w;
    ((h4*)xh)[i] = hi;
  } else {
    const size_t j = i - N4X;
    const float* Ws = (j < N4W) ? Wq : (j < 2 * N4W) ? Wk : Wv;
    const size_t jj = (j < N4W) ? j : (j < 2 * N4W) ? (j - N4W) : (j - 2 * N4W);
    const float4 v = ((const float4*)Ws)[jj];
    h4 hi;
    hi.x = (_Float16)v.x; hi.y = (_Float16)v.y;
    hi.z = (_Float16)v.z; hi.w = (_Float16)v.w;
    ((h4*)Wf)[j] = hi;
  }
}

// ---------------------------------------------------------------------------
// MFMA GEMM: C[z] = xh*W[z]^T  (f16 in, fp32 out) — m97 structure, single A.
// ---------------------------------------------------------------------------
#define GLDS(gp, lp)                                              \
  __builtin_amdgcn_global_load_lds(                               \
      (const __attribute__((address_space(1))) void*)(gp),        \
      (__attribute__((address_space(3))) void*)(lp), 16, 0, 0)

__global__ __launch_bounds__(256) void gemm_mfma(
    const _Float16* __restrict__ xh, const _Float16* __restrict__ Wf,
    float* __restrict__ Cbase) {
  __shared__ float4 lraw[1024];  // 16 KB = Ah | Bs
  _Float16* Ah = (_Float16*)lraw;
  _Float16* Bs = Ah + 4096;

  const int z = blockIdx.z;
  const _Float16* W = Wf + (size_t)z * DD * (HH * KK);
  float* C = Cbase + (size_t)z * (BB * TT) * (HH * KK);

  const int tid = threadIdx.x;
  const int w = tid >> 6;
  const int lane = tid & 63;
  const int bm = blockIdx.y * 128;
  const int bn = blockIdx.x * 128;
  const int wm = (w & 1) * 64;
  const int wn = (w >> 1) * 64;
  const int m16 = lane & 15;
  const int quad = lane >> 4;

  const _Float16* gA = xh + (size_t)(bm + (tid >> 2)) * DD + (tid & 3) * 8;
  const _Float16* gB = W + (size_t)(bn + (tid >> 2)) * DD + (tid & 3) * 8;
  const int lb = w * 512;

  v4f acc[4][4];
#pragma unroll
  for (int i = 0; i < 4; i++)
#pragma unroll
    for (int j = 0; j < 4; j++) acc[i][j] = (v4f){0.f, 0.f, 0.f, 0.f};

  for (int d0 = 0; d0 < DD; d0 += 32) {
    GLDS(gA + d0, Ah + lb);
    GLDS(gA + d0 + 64 * DD, Ah + 2048 + lb);
    GLDS(gB + d0, Bs + lb);
    GLDS(gB + d0 + 64 * DD, Bs + 2048 + lb);
    __syncthreads();
    v8h ah[4], bw[4];
#pragma unroll
    for (int i = 0; i < 4; i++) {
      ah[i] = *(const v8h*)&Ah[(wm + i * 16 + m16) * 32 + quad * 8];
      bw[i] = *(const v8h*)&Bs[(wn + i * 16 + m16) * 32 + quad * 8];
    }
#pragma unroll
    for (int mi = 0; mi < 4; mi++)
#pragma unroll
      for (int ni = 0; ni < 4; ni++)
        acc[mi][ni] = __builtin_amdgcn_mfma_f32_16x16x32_f16(ah[mi], bw[ni],
                                                             acc[mi][ni], 0, 0, 0);
    __syncthreads();
  }
#pragma unroll
  for (int mi = 0; mi < 4; mi++) {
#pragma unroll
    for (int r = 0; r < 4; r++) {
      float* cp =
          C + (size_t)(bm + wm + mi * 16 + quad * 4 + r) * (HH * KK) + bn + wn + m16;
#pragma unroll
      for (int ni = 0; ni < 4; ni++) cp[ni * 16] = acc[mi][ni][r];
    }
  }
}

// ---------------------------------------------------------------------------
// alpha/beta projections — v2: one block (4 waves) per row instead of 4
// blocks; wave g does old block-g's job. x-row reads become L1-local.
// ---------------------------------------------------------------------------
__global__ __launch_bounds__(256) void ab_proj(const float* __restrict__ x,
                                               const float* __restrict__ Wa,
                                               const float* __restrict__ ba,
                                               const float* __restrict__ Wb,
                                               const float* __restrict__ bb,
                                               float* __restrict__ abq) {
  const int row = blockIdx.x;
  const int g = threadIdx.x >> 6;
  const int lane = threadIdx.x & 63;
  const int h0 = (g & 1) * 8;
  const bool isA = (g < 2);
  const float* W = isA ? Wa : Wb;
  const float* xr = x + (size_t)row * DD;
  float acc[8];
#pragma unroll
  for (int j = 0; j < 8; j++) acc[j] = 0.f;
  for (int d = lane; d < DD; d += 64) {
    const float xv = xr[d];
#pragma unroll
    for (int j = 0; j < 8; j++)
      acc[j] = fmaf(xv, W[(size_t)(h0 + j) * DD + d], acc[j]);
  }
#pragma unroll
  for (int j = 0; j < 8; j++) {
#pragma unroll
    for (int off = 32; off > 0; off >>= 1) acc[j] += __shfl_xor(acc[j], off, 64);
  }
  if (lane == 0) {
    if (isA) {
#pragma unroll
      for (int j = 0; j < 8; j++) {
        const float z = acc[j] + ba[h0 + j];
        abq[((size_t)row * HH + h0 + j) * 4 + 0] = 1.0f / (1.0f + expf(-z));
      }
    } else {
#pragma unroll
      for (int j = 0; j < 8; j++) {
        const float z = acc[j] + bb[h0 + j];
        const float sp = (z > 20.f) ? z : log1pf(expf(z));
        abq[((size_t)row * HH + h0 + j) * 4 + 1] = sp * 0.08838834764831845f;
      }
    }
  }
}

// ---------------------------------------------------------------------------
// l2-normalize q,k in place; kq = dot(qn,kn) -> abq slot 2; slot 3 = a*b
// (pre-product so the scan's u = fma(-ab, dk, b*v) drops a chain mul).
// ---------------------------------------------------------------------------
__global__ __launch_bounds__(256) void norm_qk(float* __restrict__ q,
                                               float* __restrict__ k,
                                               float* __restrict__ abq) {
  const int vec = blockIdx.x * 4 + (threadIdx.x >> 6);
  const int l = threadIdx.x & 63;
  float* qp = q + (size_t)vec * 128;
  float* kp = k + (size_t)vec * 128;
  float q0 = qp[l], q1 = qp[l + 64];
  float k0 = kp[l], k1 = kp[l + 64];
  float sq = q0 * q0 + q1 * q1;
  float sk = k0 * k0 + k1 * k1;
#pragma unroll
  for (int off = 32; off > 0; off >>= 1) {
    sq += __shfl_xor(sq, off, 64);
    sk += __shfl_xor(sk, off, 64);
  }
  const float iq = 1.0f / fmaxf(sqrtf(sq), 1e-12f);
  const float ik = 1.0f / fmaxf(sqrtf(sk), 1e-12f);
  q0 *= iq; q1 *= iq; k0 *= ik; k1 *= ik;
  qp[l] = q0; qp[l + 64] = q1;
  kp[l] = k0; kp[l + 64] = k1;
  float pq = q0 * k0 + q1 * k1;
#pragma unroll
  for (int off = 32; off > 0; off >>= 1) pq += __shfl_xor(pq, off, 64);
  if (l == 0) {
    abq[(size_t)vec * 4 + 2] = pq;
    abq[(size_t)vec * 4 + 3] =
        abq[(size_t)vec * 4 + 0] * abq[(size_t)vec * 4 + 1];
  }
}

// ---------------------------------------------------------------------------
// Scan v10: v9 LDS-staged structure, with forced packed-f32 math.
// v9 measured ~73 VALU instr/step/wave vs ~35 static — theory: float2
// elementwise ops scalarized. Force v_pk_mul_f32 / v_pk_fma_f32 via
// register-only inline asm (no memory clobber, schedulable). Also use
// precomputed a*b (abq slot 3): u = fma(-ab, dk, b*v) — removes one mul
// from the serial recurrence chain.
// ---------------------------------------------------------------------------
#define DPP_ADD(x, ctrl)                                                     \
  ((x) + __int_as_float(__builtin_amdgcn_update_dpp(                         \
             0, __float_as_int(x), (ctrl), 0xF, 0xF, true)))

__device__ __forceinline__ float xadd32(float x) {
  // returns x[lane] + x[lane^32] in every lane (pure VALU)
  const u2v r = __builtin_amdgcn_permlane32_swap(__float_as_uint(x),
                                                 __float_as_uint(x), false,
                                                 false);
  return __uint_as_float(r.x) + __uint_as_float(r.y);
}

#define PKMUL(d, a, b) \
  asm("v_pk_mul_f32 %0, %1, %2" : "=v"(d) : "v"(a), "v"(b))
#define PKFMA3(d, a, b, c) \
  asm("v_pk_fma_f32 %0, %1, %2, %3" : "=v"(d) : "v"(a), "v"(b), "v"(c))
// acc = a*acc + c   (acc tied as dst and src1)
#define PKFMAACC(acc, a, c) \
  asm("v_pk_fma_f32 %0, %1, %0, %2" : "+v"(acc) : "v"(a), "v"(c))

#define SBAR() asm volatile("s_barrier" ::: "memory")
#define WAITV(n) asm volatile("s_waitcnt vmcnt(" #n ")" ::: "memory")

// one recurrence step; sources already in registers
#define SCAN_MATH(kc, qc, vc, ac, jj, obname)                                  \
  {                                                                            \
    const f2 ka = {kc.x, kc.y};                                                \
    const f2 kb2 = {kc.z, kc.w};                                               \
    const f2 qa = {qc.x, qc.y};                                                \
    const f2 qb2 = {qc.z, qc.w};                                               \
    f2 t0, t1, pdk, pdq;                                                       \
    PKMUL(t0, Sa, ka);                                                         \
    PKFMA3(pdk, Sb, kb2, t0);                                                  \
    PKMUL(t1, Sa, qa);                                                         \
    PKFMA3(pdq, Sb, qb2, t1);                                                  \
    float dk = pdk.x + pdk.y;                                                  \
    float dq = pdq.x + pdq.y;                                                  \
    const float ayv = ac.y * vc;                                               \
    dk = DPP_ADD(dk, 0xB1);  dq = DPP_ADD(dq, 0xB1);   /* width 2  */          \
    dk = DPP_ADD(dk, 0x4E);  dq = DPP_ADD(dq, 0x4E);   /* width 4  */          \
    dk = DPP_ADD(dk, 0x141); dq = DPP_ADD(dq, 0x141);  /* width 8  */          \
    dk = DPP_ADD(dk, 0x140); dq = DPP_ADD(dq, 0x140);  /* width 16 */          \
    dk = xadd32(dk);         dq = xadd32(dq);          /* width 32 */          \
    const float u = fmaf(-ac.w, dk, ayv);                                      \
    const float oo = fmaf(ac.x, dq, u * ac.z);                                 \
    const f2 a2 = {ac.x, ac.x};                                                \
    const f2 u2 = {u, u};                                                      \
    f2 uk0, uk1;                                                               \
    PKMUL(uk0, u2, ka);                                                        \
    PKFMAACC(Sa, a2, uk0);                                                     \
    PKMUL(uk1, u2, kb2);                                                       \
    PKFMAACC(Sb, a2, uk1);                                                     \
    obname = (ks == (jj)) ? oo : obname;                                       \
  }

// stage 8-step group starting at row tg into buffer bi (3 GLDS + 8 v-loads)
#define STAGE(bi, tg)                                                          \
  {                                                                            \
    const float* gk =                                                          \
        kU + (size_t)((tg) + 2 * w + (lane >> 5)) * 2048 + (lane & 31) * 4;    \
    GLDS(gk, &Kb[bi][2 * w][0]);                                               \
    const float* gq =                                                          \
        qU + (size_t)((tg) + 2 * w + (lane >> 5)) * 2048 + (lane & 31) * 4;    \
    GLDS(gq, &Qb[bi][2 * w][0]);                                               \
    if (lane < 8) GLDS(aU + (size_t)((tg) + lane) * 64, &Ab[bi][0][0]);        \
    _Pragma("unroll") for (int jj = 0; jj < 8; jj++)                           \
        vf##bi[jj] = vU[vrow + (size_t)((tg) + jj) * 2048];                    \
  }

#define COMPUTE_GROUP(bi, obname)                                              \
  float obname = 0.f;                                                          \
  _Pragma("unroll") for (int j = 0; j < 8; j++) {                              \
    const float4 kc = *(const float4*)&Kb[bi][j][ks4];                         \
    const float4 qc = *(const float4*)&Qb[bi][j][ks4];                         \
    const float4 ac = *(const float4*)&Ab[bi][j][0];                           \
    const float vc = vf##bi[j];                                                \
    SCAN_MATH(kc, qc, vc, ac, j, obname);                                      \
  }

__global__ __launch_bounds__(256, 2) void scan_kernel(
    const float* __restrict__ q, const float* __restrict__ k,
    const float* __restrict__ v, const float* __restrict__ abq,
    float* __restrict__ o) {
  __shared__ float Kb[2][8][128];  // 4 KB per buffer
  __shared__ float Qb[2][8][128];  // 4 KB per buffer
  __shared__ float Ab[2][8][4];    // 128 B per buffer

  const int bid = blockIdx.x;  // = s*32 + bh
  const int bh = bid & 31;
  const int s = bid >> 5;  // 0..15
  const int h = bh & 15;
  const int b = bh >> 4;
  const int tid = threadIdx.x;
  const int w = tid >> 6;
  const int lane = tid & 63;
  const int rg = (lane >> 4) & 1;                   // row within wave (0..1)
  const int ks = (lane & 15) | ((lane >> 5) << 4);  // k-slot 0..31 (4 floats)
  const int ks4 = ks * 4;
  const int vrow = s * 8 + w * 2 + rg;

  const size_t base = (size_t)b * TT * 2048 + (size_t)h * KK;
  const float* kU = k + base;
  const float* qU = q + base;
  const float* vU = v + base;
  const float* aU = abq + ((size_t)b * TT * HH + h) * 4;
  float* oU = o + base;

  f2 Sa = {0.f, 0.f}, Sb = {0.f, 0.f};
  float vf0[8], vf1[8];

  // prologue: stage groups 0 and 1 (11 loads/group per wave)
  STAGE(0, 0);
  STAGE(1, 8);
  WAITV(11);  // group 0's 11 loads complete (group 1's 11 still in flight)
  SBAR();
  __builtin_amdgcn_sched_barrier(0);

  int tg = 0;  // first row of current even group
  for (int gp = 0; gp < TT / 8; gp += 2) {
    // ---- even group (buffer 0)
    COMPUTE_GROUP(0, ob0);
    if (ks < 8) oU[vrow + (size_t)(tg + ks) * 2048] = ob0;
    SBAR();  // all waves done reading buf0 -> safe to overwrite
    if (gp + 2 < TT / 8) {
      STAGE(0, tg + 16);
      WAITV(11);  // odd group's loads (issued last round) complete
    } else {
      WAITV(0);
    }
    SBAR();  // buf1 ready for everyone
    __builtin_amdgcn_sched_barrier(0);

    // ---- odd group (buffer 1)
    COMPUTE_GROUP(1, ob1);
    if (ks < 8) oU[vrow + (size_t)(tg + 8 + ks) * 2048] = ob1;
    SBAR();
    if (gp + 3 < TT / 8) {
      STAGE(1, tg + 24);
      WAITV(11);
    } else {
      WAITV(0);
    }
    SBAR();
    __builtin_amdgcn_sched_barrier(0);

    tg += 16;
  }
}

// ---------------------------------------------------------------------------
extern "C" void kernel_launch(void* const* d_in, const int* in_sizes, int n_in,
                              void* d_out, int out_size, void* d_ws,
                              size_t ws_size, hipStream_t stream) {
  const float* x = (const float*)d_in[0];
  const float* Wq = (const float*)d_in[1];
  const float* Wk = (const float*)d_in[2];
  const float* Wv = (const float*)d_in[3];
  const float* Wa = (const float*)d_in[4];
  const float* ba = (const float*)d_in[5];
  const float* Wb = (const float*)d_in[6];
  const float* bb = (const float*)d_in[7];
  float* out = (float*)d_out;
  float* ws = (float*)d_ws;

  const size_t PROJ = (size_t)BB * TT * HH * KK;  // 8,388,608
  const size_t NABQ = (size_t)BB * TT * HH * 4;
  float* qw = ws;
  float* kw = ws + PROJ;
  float* vw = ws + 2 * PROJ;
  float* abq = ws + 3 * PROJ;
  _Float16* xh = (_Float16*)(abq + NABQ);
  _Float16* Wf = xh + (size_t)BB * TT * DD;
  const size_t NEED = (3 * PROJ + NABQ) * 4 +
                      ((size_t)BB * TT * DD + 3 * (size_t)(HH * KK) * DD) * 2;

  const int M = BB * TT;  // 4096
  const int N = HH * KK;  // 2048
  if (ws_size >= NEED) {
    const int cgrid = (int)(((size_t)BB * TT * DD / 4 + 3 * (size_t)N * DD / 4) / 256);
    convert_f16<<<cgrid, 256, 0, stream>>>(x, Wq, Wk, Wv, xh, Wf);
    gemm_mfma<<<dim3(N / 128, M / 128, 3), 256, 0, stream>>>(xh, Wf, qw);
  } else {
    gemm_nt3<<<dim3(N / 128, M / 128, 3), 256, 0, stream>>>(x, Wq, Wk, Wv, qw,
                                                            M, N, DD);
  }
  ab_proj<<<M, 256, 0, stream>>>(x, Wa, ba, Wb, bb, abq);
  norm_qk<<<(BB * TT * HH) / 4, 256, 0, stream>>>(qw, kw, abq);
  scan_kernel<<<BB * HH * 16, 256, 0, stream>>>(qw, kw, vw, abq, out);
}